// Round 5
// baseline (71.310 us; speedup 1.0000x reference)
//
#include <hip/hip_runtime.h>
#include <hip/hip_bf16.h>

typedef __attribute__((ext_vector_type(8))) short short8;
typedef __attribute__((ext_vector_type(4))) float f32x4;

#define TEMP_INV 20.0f
#define NCH 256

__device__ inline unsigned short f2bf(float f){
    unsigned int u = __builtin_bit_cast(unsigned int, f);
    u += 0x7fffu + ((u >> 16) & 1u);
    return (unsigned short)(u >> 16);
}
__device__ inline float bf2f(unsigned short h){
    unsigned int u = ((unsigned int)h) << 16;
    return __builtin_bit_cast(float, u);
}
__device__ inline unsigned int pk2bf(float a, float b){
    return (unsigned int)f2bf(a) | ((unsigned int)f2bf(b) << 16);
}

#define GLOAD16(src, dst) __builtin_amdgcn_global_load_lds( \
    (const __attribute__((address_space(1))) unsigned int*)(src), \
    (__attribute__((address_space(3))) unsigned int*)(dst), 16, 0, 0)

// ---------------------------------------------------------------------------
// k_norm: normalize query rows -> bf16 A, pre-swizzled per-64-col K-chunk
// tiles [12][256][64] so k_main can global_load_lds linearly. Also zeroes
// the output scalar (k_lse atomicAdds into it).
// ---------------------------------------------------------------------------
__global__ __launch_bounds__(256) void k_norm(const float* __restrict__ q,
                                              unsigned short* __restrict__ Aswz,
                                              float* __restrict__ out){
    int b = blockIdx.x, t = threadIdx.x;
    if (b == 0 && t == 0) out[0] = 0.f;
    const float* qr = q + b * 768;
    float v0 = qr[t], v1 = qr[t + 256], v2 = qr[t + 512];
    float ss = v0*v0 + v1*v1 + v2*v2;
#pragma unroll
    for (int o = 32; o; o >>= 1) ss += __shfl_xor(ss, o);
    __shared__ float red[4];
    if ((t & 63) == 0) red[t >> 6] = ss;
    __syncthreads();
    ss = red[0] + red[1] + red[2] + red[3];
    float inv = 1.0f / fmaxf(sqrtf(ss), 1e-8f);
    float nv[3] = {v0 * inv, v1 * inv, v2 * inv};
#pragma unroll
    for (int j = 0; j < 3; j++){
        int cc = t + 256 * j;
        unsigned short h = f2bf(nv[j]);
        int kc = cc >> 6, kl = cc & 63, g = kl >> 3, e = kl & 7;
        int slot = g ^ (b & 7);
        Aswz[kc * 16384 + b * 64 + slot * 8 + e] = h;
    }
}

// ---------------------------------------------------------------------------
// k_main: 256 blocks x 1024 threads (16 waves, 1 block/CU). Block b owns
// combined columns [257b, 257b+257): 256 via two 256x128 MFMA passes
// (on-the-fly B row-norm), col 257b+256 via distributed bf16 dot.
// Decoupled pipeline: step s stages B(s+1) into Btile[(s+1)&1] (from regs
// loaded at step s-1) while MFMA consumes tiles staged LAST step
// (Atile[s&1], Btile[s&1]). One barrier per step; counted vmcnt(4).
// ---------------------------------------------------------------------------
__global__ __launch_bounds__(1024, 1) void k_main(
        const float* __restrict__ keys,
        const float* __restrict__ queue,
        const unsigned short* __restrict__ Aswz,
        float* __restrict__ pmax,
        float* __restrict__ psum,
        float* __restrict__ diag){
    __shared__ unsigned short Atile[2][16384]; // 64 KB dbuf [256][64] swizzled
    __shared__ unsigned short Btile[2][8192];  // 32 KB dbuf [128][64] swizzled
    __shared__ float bxnf[768];
    __shared__ unsigned short bxn16[768];
    __shared__ float invn[128];
    __shared__ float redm[4][256];
    __shared__ float reds[4][256];
    __shared__ float xred[4][256];
    __shared__ float wred[16];
    __shared__ float sxs;

    const int b = blockIdx.x, t = threadIdx.x;
    const int lane = t & 63;
    const int w = t >> 6;                 // 0..15
    const int wm = w >> 2, wn = w & 3;    // 4m x 4n waves, each 64x32
    const int frow = lane & 15, fg = lane >> 4;
    const int c = t >> 3, q8 = t & 7;     // B staging: 8 threads/col
    const int c7 = c & 7;

    // ----- prologue: extra column (queue row 257*b), normalized, bf16 ------
    size_t rx = (size_t)b * 257;
    float ssx = 0.f;
    if (t < 768){ float v = queue[rx * 768 + t]; bxnf[t] = v; ssx = v * v; }
#pragma unroll
    for (int o = 32; o; o >>= 1) ssx += __shfl_xor(ssx, o);
    if (lane == 0) wred[w] = ssx;
    __syncthreads();
    if (t == 0){
        float s = 0.f;
#pragma unroll
        for (int i = 0; i < 16; i++) s += wred[i];
        sxs = 1.0f / fmaxf(sqrtf(s), 1e-8f);
    }
    __syncthreads();
    if (t < 768) bxn16[t] = f2bf(bxnf[t] * sxs);
    __syncthreads();

    // ----- B row pointers for the two column halves -----
    long n0 = (long)b * 257 + c;
    long n1 = n0 + 128;
    const float* rp0 = ((n0 < 256) ? (keys + n0 * 768)
                                   : (queue + (size_t)(n0 - 256) * 768)) + q8 * 4;
    const float* rp1 = ((n1 < 256) ? (keys + n1 * 768)
                                   : (queue + (size_t)(n1 - 256) * 768)) + q8 * 4;

    float ssqA = 0.f, ssqB = 0.f;

    // stage-write helper: convert 2 float4 -> bf16, swizzled ds_write
    auto stageB = [&](unsigned short* bt, float4 u0, float4 u1, float& sq){
        sq += u0.x*u0.x + u0.y*u0.y + u0.z*u0.z + u0.w*u0.w;
        sq += u1.x*u1.x + u1.y*u1.y + u1.z*u1.z + u1.w*u1.w;
        int slot0 = (q8 >> 1) ^ c7;
        int slot1 = ((q8 + 8) >> 1) ^ c7;
        uint2 pk0, pk1;
        pk0.x = pk2bf(u0.x, u0.y); pk0.y = pk2bf(u0.z, u0.w);
        pk1.x = pk2bf(u1.x, u1.y); pk1.y = pk2bf(u1.z, u1.w);
        *(uint2*)&bt[c * 64 + slot0 * 8 + (q8 & 1) * 4] = pk0;
        *(uint2*)&bt[c * 64 + slot1 * 8 + (q8 & 1) * 4] = pk1;
    };

    // ----- staging prologue: A(0), B(0) now; B(1) in flight -----
    {
        const unsigned short* gA = Aswz + t * 8;
        GLOAD16(gA, &Atile[0][t * 8]);
        GLOAD16(gA + 8192, &Atile[0][t * 8 + 8192]);
    }
    float4 cur0 = *(const float4*)(rp0);
    float4 cur1 = *(const float4*)(rp0 + 32);
    float4 nxt0 = *(const float4*)(rp0 + 64);
    float4 nxt1 = *(const float4*)(rp0 + 96);
    asm volatile("s_waitcnt vmcnt(2)" ::: "memory");  // A(0), B(0) done
    stageB(Btile[0], cur0, cur1, ssqA);
    asm volatile("s_waitcnt lgkmcnt(0)" ::: "memory");
    __builtin_amdgcn_s_barrier();
    asm volatile("" ::: "memory");
    cur0 = nxt0; cur1 = nxt1;                         // cur = B(1)

    float Mrun = -1e30f, Srun = 0.f;
    float dx = 0.f;
    const int xrow = t & 255, xk = t >> 8;

    f32x4 acc[4][2];
#pragma unroll
    for (int i = 0; i < 4; i++)
#pragma unroll
        for (int j = 0; j < 2; j++) acc[i][j] = (f32x4)0.f;

    for (int s = 0; s < 24; ++s){
        // (a) issue A(s+1) -> Atile[(s+1)&1]
        if (s < 23){
            int kcn = (s + 1) % 12;
            const unsigned short* gA = Aswz + kcn * 16384 + t * 8;
            unsigned short* lA = &Atile[(s + 1) & 1][t * 8];
            GLOAD16(gA, lA);
            GLOAD16(gA + 8192, lA + 8192);
        }
        // (b) issue B(s+2) reg loads
        float4 nb0 = cur0, nb1 = cur1;
        if (s < 22){
            int u = s + 2;
            const float* rpu = (u < 12) ? rp0 : rp1;
            int kcu = (u < 12) ? u : (u - 12);
            nb0 = *(const float4*)(rpu + kcu * 64);
            nb1 = *(const float4*)(rpu + kcu * 64 + 32);
        }
        // (c) counted wait: A(s) LDS-writes + B(s+1) regs complete
        if (s < 22)       asm volatile("s_waitcnt vmcnt(4)" ::: "memory");
        else if (s == 22) asm volatile("s_waitcnt vmcnt(2)" ::: "memory");
        else              asm volatile("s_waitcnt vmcnt(0)" ::: "memory");

        // (d) stage B(s+1) -> Btile[(s+1)&1]
        if (s < 23){
            int u = s + 1;
            if (u < 12) stageB(Btile[(s + 1) & 1], cur0, cur1, ssqA);
            else        stageB(Btile[(s + 1) & 1], cur0, cur1, ssqB);
        }

        // (e) MFMA on tiles staged last step: Atile[s&1], Btile[s&1]
        const unsigned short* At = Atile[s & 1];
        const unsigned short* Bt = Btile[s & 1];
#pragma unroll
        for (int ks = 0; ks < 2; ++ks){
            short8 af[4], bfv[2];
#pragma unroll
            for (int fm = 0; fm < 4; ++fm){
                int row = wm * 64 + fm * 16 + frow;
                int slot = (ks * 4 + fg) ^ (frow & 7);
                af[fm] = *(const short8*)&At[row * 64 + slot * 8];
            }
#pragma unroll
            for (int fn = 0; fn < 2; ++fn){
                int row = wn * 32 + fn * 16 + frow;
                int slot = (ks * 4 + fg) ^ (frow & 7);
                bfv[fn] = *(const short8*)&Bt[row * 64 + slot * 8];
            }
#pragma unroll
            for (int fm = 0; fm < 4; ++fm)
#pragma unroll
                for (int fn = 0; fn < 2; ++fn)
                    acc[fm][fn] = __builtin_amdgcn_mfma_f32_16x16x32_bf16(
                        af[fm], bfv[fn], acc[fm][fn], 0, 0, 0);
        }

        // (f) extra-column dot partials (pass 0 steps cover all kc once)
        if (s < 12){
#pragma unroll
            for (int gi = 0; gi < 2; ++gi){
                int g = xk * 2 + gi;
                short8 av = *(const short8*)&At[xrow * 64 + (g ^ (xrow & 7)) * 8];
                short8 xv = *(const short8*)&bxn16[s * 64 + g * 8];
#pragma unroll
                for (int e = 0; e < 8; ++e)
                    dx += bf2f((unsigned short)av[e]) * bf2f((unsigned short)xv[e]);
            }
        }

        asm volatile("s_waitcnt lgkmcnt(0)" ::: "memory");
        __builtin_amdgcn_s_barrier();
        asm volatile("" ::: "memory");
        cur0 = nb0; cur1 = nb1;

        // ---- pass-0 epilogue after step 11 ----
        if (s == 11){
            float sq = ssqA;
            sq += __shfl_xor(sq, 1);
            sq += __shfl_xor(sq, 2);
            sq += __shfl_xor(sq, 4);
            if (q8 == 0) invn[c] = 1.0f / fmaxf(sqrtf(sq), 1e-8f);
            xred[xk][xrow] = dx;
            __syncthreads();
#pragma unroll
            for (int fm = 0; fm < 4; ++fm){
#pragma unroll
                for (int rr = 0; rr < 4; ++rr){
                    float v0 = acc[fm][0][rr] * invn[wn * 32 + frow] * TEMP_INV;
                    float v1 = acc[fm][1][rr] * invn[wn * 32 + 16 + frow] * TEMP_INV;
                    int row = wm * 64 + fm * 16 + fg * 4 + rr;
                    if (b == 0){
                        int col0 = wn * 32 + frow;
                        if (row == col0)      diag[row] = v0;
                        if (row == col0 + 16) diag[row] = v1;
                    }
                    float m = fmaxf(v0, v1);
#pragma unroll
                    for (int o = 1; o < 16; o <<= 1) m = fmaxf(m, __shfl_xor(m, o));
                    float sex = __expf(v0 - m) + __expf(v1 - m);
#pragma unroll
                    for (int o = 1; o < 16; o <<= 1) sex += __shfl_xor(sex, o);
                    if (frow == 0){ redm[wn][row] = m; reds[wn][row] = sex; }
                }
            }
            __syncthreads();
            if (t < 256){
#pragma unroll
                for (int ww = 0; ww < 4; ++ww){
                    float m2 = redm[ww][t], s2 = reds[ww][t];
                    float M = fmaxf(Mrun, m2);
                    Srun = Srun * __expf(Mrun - M) + s2 * __expf(m2 - M);
                    Mrun = M;
                }
            }
            __syncthreads();
#pragma unroll
            for (int i = 0; i < 4; i++)
#pragma unroll
                for (int j = 0; j < 2; j++) acc[i][j] = (f32x4)0.f;
        }
    }

    // ---- pass-1 epilogue ----
    {
        float sq = ssqB;
        sq += __shfl_xor(sq, 1);
        sq += __shfl_xor(sq, 2);
        sq += __shfl_xor(sq, 4);
        if (q8 == 0) invn[c] = 1.0f / fmaxf(sqrtf(sq), 1e-8f);
        __syncthreads();
#pragma unroll
        for (int fm = 0; fm < 4; ++fm){
#pragma unroll
            for (int rr = 0; rr < 4; ++rr){
                float v0 = acc[fm][0][rr] * invn[wn * 32 + frow] * TEMP_INV;
                float v1 = acc[fm][1][rr] * invn[wn * 32 + 16 + frow] * TEMP_INV;
                int row = wm * 64 + fm * 16 + fg * 4 + rr;
                if (b == 0){
                    int col0 = 128 + wn * 32 + frow;
                    if (row == col0)      diag[row] = v0;
                    if (row == col0 + 16) diag[row] = v1;
                }
                float m = fmaxf(v0, v1);
#pragma unroll
                for (int o = 1; o < 16; o <<= 1) m = fmaxf(m, __shfl_xor(m, o));
                float sex = __expf(v0 - m) + __expf(v1 - m);
#pragma unroll
                for (int o = 1; o < 16; o <<= 1) sex += __shfl_xor(sex, o);
                if (frow == 0){ redm[wn][row] = m; reds[wn][row] = sex; }
            }
        }
        __syncthreads();
        if (t < 256){
#pragma unroll
            for (int ww = 0; ww < 4; ++ww){
                float m2 = redm[ww][t], s2 = reds[ww][t];
                float M = fmaxf(Mrun, m2);
                Srun = Srun * __expf(Mrun - M) + s2 * __expf(m2 - M);
                Mrun = M;
            }
        }
    }

    // ----- final merge with extra column -----
    if (t < 256){
        float vx = (xred[0][t] + xred[1][t] + xred[2][t] + xred[3][t]) * TEMP_INV;
        float M = fmaxf(Mrun, vx);
        float S = Srun * __expf(Mrun - M) + __expf(vx - M);
        pmax[b * 256 + t] = M;
        psum[b * 256 + t] = S;
    }
}

// ---------------------------------------------------------------------------
// k_lse: per q-row, merge 256 chunk partials; atomicAdd loss contribution.
// ---------------------------------------------------------------------------
__global__ __launch_bounds__(256) void k_lse(const float* __restrict__ pmax,
                                             const float* __restrict__ psum,
                                             const float* __restrict__ diag,
                                             float* __restrict__ out){
    int b = blockIdx.x, t = threadIdx.x;
    float m = -1e30f;
    for (int cc = t; cc < NCH; cc += 256) m = fmaxf(m, pmax[cc * 256 + b]);
#pragma unroll
    for (int o = 32; o; o >>= 1) m = fmaxf(m, __shfl_xor(m, o));
    __shared__ float red[4];
    __shared__ float Msh;
    if ((t & 63) == 0) red[t >> 6] = m;
    __syncthreads();
    if (t == 0) Msh = fmaxf(fmaxf(red[0], red[1]), fmaxf(red[2], red[3]));
    __syncthreads();
    float M = Msh;
    float s = 0.f;
    for (int cc = t; cc < NCH; cc += 256) s += psum[cc * 256 + b] * __expf(pmax[cc * 256 + b] - M);
#pragma unroll
    for (int o = 32; o; o >>= 1) s += __shfl_xor(s, o);
    if ((t & 63) == 0) red[t >> 6] = s;
    __syncthreads();
    if (t == 0)
        atomicAdd(out, (M + logf(red[0] + red[1] + red[2] + red[3]) - diag[b]) * (1.0f / 256.0f));
}

extern "C" void kernel_launch(void* const* d_in, const int* in_sizes, int n_in,
                              void* d_out, int out_size, void* d_ws, size_t ws_size,
                              hipStream_t stream){
    const float* q  = (const float*)d_in[0];
    const float* k  = (const float*)d_in[1];
    const float* qu = (const float*)d_in[2];
    char* ws = (char*)d_ws;
    // ws layout (bytes): Aswz 0..393216 | diag ..394240 | pmax ..656384
    //                    psum ..918528
    unsigned short* Aswz = (unsigned short*)(ws);
    float* diag  = (float*)(ws + 393216);
    float* pmax  = (float*)(ws + 394240);
    float* psum  = (float*)(ws + 656384);

    k_norm<<<256, 256, 0, stream>>>(q, Aswz, (float*)d_out);
    k_main<<<256, 1024, 0, stream>>>(k, qu, Aswz, pmax, psum, diag);
    k_lse<<<256, 256, 0, stream>>>(pmax, psum, diag, (float*)d_out);
}